// Round 5
// baseline (231.298 us; speedup 1.0000x reference)
//
#include <hip/hip_runtime.h>
#include <hip/hip_bf16.h>
#include <stdint.h>

// Problem constants (B=8192, I=512, H=1024, D=8)
#define B_N 8192
#define I_N 512
#define H_N 1024
// Concatenated K = 512 + 1024 = 1536 = 48 kb-chunks of 32.

typedef __bf16 bf16x8 __attribute__((ext_vector_type(8)));
typedef float f32x4 __attribute__((ext_vector_type(4)));
typedef unsigned short u16;
typedef unsigned int u32;

__device__ inline u16 f2bf(float f) {
  __hip_bfloat16 h = __float2bfloat16(f);
  return __builtin_bit_cast(u16, h);
}

__device__ inline float bf2f(u16 b) {
  unsigned int u = ((unsigned int)b) << 16;
  return __builtin_bit_cast(float, u);
}

// Fragment-major layouts (one MFMA 16x16x32 A/B fragment = 64 lanes x 8 bf16 = 1 KB contiguous):
//   acat[(R*48 + kb)*512 + lane*8] : lane -> row R*16+(lane&15), k = kb*32+(lane>>4)*8+i
//     kb<16: k from x (K=512); kb>=16: from hdec col jh = (kb-16)*32+(lane>>4)*8+i
//   wcat[((g*64 + C)*48 + kb)*512 + lane*8] : lane -> out-col C*16+(lane&15), same k split
//     (weight row j = gc*16+(lane&15), gc = g*64+C, since W rows are [3H] = gate-major)

// ---------- build x-part of acat + all of wcat (one wave builds one 1KB fragment) ----------
__global__ void cvt_frag(const float* __restrict__ x, const float* __restrict__ wih,
                         const float* __restrict__ whh,
                         u16* __restrict__ acat, u16* __restrict__ wcat) {
  int fid = blockIdx.x * 4 + (threadIdx.x >> 6);
  int l = threadIdx.x & 63;
  int lr = l & 15, lk = (l >> 4) * 8;
  const float* src;
  u16* dst;
  if (fid < 8192) {                       // x fragments: R in [0,512), kb in [0,16)
    int R = fid >> 4, kb = fid & 15;
    src = x + (size_t)(R * 16 + lr) * I_N + kb * 32 + lk;
    dst = acat + (((size_t)(R * 48 + kb)) << 9) + l * 8;
  } else {                                // W fragments: wf = (g*64+C)*48 + kb
    int wf = fid - 8192;                  // [0, 9216)
    int kb = wf % 48, gc = wf / 48;
    if (kb < 16) src = wih + (size_t)(gc * 16 + lr) * I_N + kb * 32 + lk;
    else         src = whh + (size_t)(gc * 16 + lr) * H_N + (kb - 16) * 32 + lk;
    dst = wcat + (((size_t)wf) << 9) + l * 8;
  }
  float4 a0 = *(const float4*)src;
  float4 a1 = *(const float4*)(src + 4);
  union { u16 u[8]; float4 v; } pk;
  pk.u[0] = f2bf(a0.x); pk.u[1] = f2bf(a0.y); pk.u[2] = f2bf(a0.z); pk.u[3] = f2bf(a0.w);
  pk.u[4] = f2bf(a1.x); pk.u[5] = f2bf(a1.y); pk.u[6] = f2bf(a1.z); pk.u[7] = f2bf(a1.w);
  *(float4*)dst = pk.v;
}

// ---------- decay: hdec = exp(-relu(delta @ Wg^T + bg)) * h ----------
// Writes BOTH the h-part of acat (fragment-major, for GEMM A) and row-major bf16 (for epilogue).
__global__ void decay_frag(const float* __restrict__ h, const float* __restrict__ delta,
                           const float* __restrict__ wg, const float* __restrict__ bg,
                           u16* __restrict__ acat, u16* __restrict__ hdecRM) {
  int b = blockIdx.x;                 // 4096 blocks: R in [0,512) x col-quarter in [0,8)
  int R = b >> 3, cq = b & 7;
  int l = threadIdx.x & 63, fq = threadIdx.x >> 6;
  int kh = cq * 4 + fq;               // h-col chunk in [0,32)
  int row = R * 16 + (l & 15);
  int jc = kh * 32 + (l >> 4) * 8;    // 8 consecutive hdec cols
  float4 d0 = *(const float4*)(delta + (size_t)row * 8);
  float4 d1 = *(const float4*)(delta + (size_t)row * 8 + 4);
  const float* hp = h + (size_t)row * H_N + jc;
  float4 h0 = *(const float4*)hp, h1 = *(const float4*)(hp + 4);
  float hv[8] = {h0.x, h0.y, h0.z, h0.w, h1.x, h1.y, h1.z, h1.w};
  float4 bg0 = *(const float4*)(bg + jc);
  float4 bg1 = *(const float4*)(bg + jc + 4);
  float bgl[8] = {bg0.x, bg0.y, bg0.z, bg0.w, bg1.x, bg1.y, bg1.z, bg1.w};
  union { u16 u[8]; float4 v; } o;
#pragma unroll
  for (int i = 0; i < 8; ++i) {
    const float4* wr = (const float4*)(wg + (size_t)(jc + i) * 8);
    float4 w0 = wr[0], w1 = wr[1];
    float t = d0.x*w0.x + d0.y*w0.y + d0.z*w0.z + d0.w*w0.w
            + d1.x*w1.x + d1.y*w1.y + d1.z*w1.z + d1.w*w1.w + bgl[i];
    t = t > 0.0f ? t : 0.0f;
    o.u[i] = f2bf(__expf(-t) * hv[i]);
  }
  *(float4*)(acat + (((size_t)(R * 48 + 16 + kh)) << 9) + l * 8) = o.v;
  *(float4*)(hdecRM + (size_t)row * H_N + jc) = o.v;
}

// ---------- barrier-free fragment GEMM + fused GRU epilogue ----------
// Block: 128 rows x 64 cols, 4 waves, wave tile 64x32. No LDS, no __syncthreads:
// fragments read straight from L2 (frag-major, coalesced dwordx4), 2-stage register
// double buffer, compiler emits fine-grained vmcnt. 4 acc sets: r,z over full K=1536
// (gi+gh fused by K-concatenation); n split into i_n (kb<16) and h_n (kb>=16).
__global__ __launch_bounds__(256, 2) void gru_gemm(
    const u16* __restrict__ acat, const u16* __restrict__ wcat,
    const u16* __restrict__ hdecRM,
    const float* __restrict__ bih, const float* __restrict__ bhh,
    float* __restrict__ out) {
  const int tid = threadIdx.x, lane = tid & 63, wave = tid >> 6;
  const int wm = wave & 1, wn = wave >> 1;
  const int Rb = blockIdx.x * 8 + wm * 4;   // base 16-row block
  const int Cb = blockIdx.y * 4 + wn * 2;   // base 16-col block
  const u16* aP = acat + (((size_t)Rb * 48) << 9) + lane * 8;
  const u16* wP = wcat + (((size_t)Cb * 48) << 9) + lane * 8;

  f32x4 aR[4][2], aZ[4][2], aN1[4][2], aN2[4][2];
#pragma unroll
  for (int rb = 0; rb < 4; ++rb)
#pragma unroll
    for (int cb = 0; cb < 2; ++cb)
#pragma unroll
      for (int r = 0; r < 4; ++r) {
        aR[rb][cb][r] = 0.0f; aZ[rb][cb][r] = 0.0f;
        aN1[rb][cb][r] = 0.0f; aN2[rb][cb][r] = 0.0f;
      }

  bf16x8 af[2][4];
  bf16x8 wf[2][6];   // [g*2+cb]: r:0,1  z:2,3  n:4,5

#define LOADF(P, KB)                                                            \
  {                                                                             \
    _Pragma("unroll")                                                           \
    for (int rb = 0; rb < 4; ++rb)                                              \
      af[P][rb] = *(const bf16x8*)(aP + ((rb * 48 + (KB)) << 9));               \
    _Pragma("unroll")                                                           \
    for (int g = 0; g < 3; ++g)                                                 \
      _Pragma("unroll")                                                         \
      for (int cb = 0; cb < 2; ++cb)                                            \
        wf[P][g * 2 + cb] = *(const bf16x8*)(wP + (((g * 64 + cb) * 48 + (KB)) << 9)); \
  }

#define MATH(P, ACCN)                                                           \
  {                                                                             \
    _Pragma("unroll")                                                           \
    for (int rb = 0; rb < 4; ++rb) {                                            \
      _Pragma("unroll")                                                         \
      for (int cb = 0; cb < 2; ++cb) {                                          \
        aR[rb][cb] = __builtin_amdgcn_mfma_f32_16x16x32_bf16(af[P][rb], wf[P][cb],     aR[rb][cb], 0, 0, 0); \
        aZ[rb][cb] = __builtin_amdgcn_mfma_f32_16x16x32_bf16(af[P][rb], wf[P][2 + cb], aZ[rb][cb], 0, 0, 0); \
        ACCN[rb][cb] = __builtin_amdgcn_mfma_f32_16x16x32_bf16(af[P][rb], wf[P][4 + cb], ACCN[rb][cb], 0, 0, 0); \
      }                                                                         \
    }                                                                           \
  }

  LOADF(0, 0)
  // x-region: kb in [0,16), n-gate -> aN1 (i_n)
  for (int kb = 0; kb < 16; kb += 2) {
    LOADF(1, kb + 1)
    MATH(0, aN1)
    LOADF(0, kb + 2)     // kb=14 body loads kb=16: seamless x->h handoff
    MATH(1, aN1)
  }
  // h-region: kb in [16,48), n-gate -> aN2 (h_n)
  for (int kb = 16; kb < 48; kb += 2) {
    LOADF(1, kb + 1)
    MATH(0, aN2)
    LOADF(0, kb + 2)     // final prefetch kb=48 lands in adjacent ws region: harmless
    MATH(1, aN2)
  }
#undef LOADF
#undef MATH

  // ---- epilogue: gates + output. C/D: col=lane&15, row=(lane>>4)*4+reg ----
#pragma unroll
  for (int cb = 0; cb < 2; ++cb) {
    const int col = (Cb + cb) * 16 + (lane & 15);
    const float b_r  = bih[col] + bhh[col];
    const float b_z  = bih[H_N + col] + bhh[H_N + col];
    const float b_in = bih[2 * H_N + col];
    const float b_hn = bhh[2 * H_N + col];
#pragma unroll
    for (int rb = 0; rb < 4; ++rb) {
      const int rbase = (Rb + rb) * 16 + ((lane >> 4) << 2);
#pragma unroll
      for (int r = 0; r < 4; ++r) {
        const int row = rbase + r;
        float rg = 1.0f / (1.0f + __expf(-(aR[rb][cb][r] + b_r)));
        float zg = 1.0f / (1.0f + __expf(-(aZ[rb][cb][r] + b_z)));
        float s  = (aN1[rb][cb][r] + b_in) + rg * (aN2[rb][cb][r] + b_hn);
        float e  = __expf(2.0f * s);
        float ng = (e - 1.0f) / (e + 1.0f);   // tanh(s), stable both tails
        float hv = bf2f(hdecRM[(size_t)row * H_N + col]);
        out[(size_t)row * H_N + col] = ng + zg * (hv - ng);
      }
    }
  }
}

extern "C" void kernel_launch(void* const* d_in, const int* in_sizes, int n_in,
                              void* d_out, int out_size, void* d_ws, size_t ws_size,
                              hipStream_t stream) {
  const float* x     = (const float*)d_in[0];
  const float* delta = (const float*)d_in[1];
  const float* h     = (const float*)d_in[2];
  const float* wih   = (const float*)d_in[3];
  const float* whh   = (const float*)d_in[4];
  const float* bih   = (const float*)d_in[5];
  const float* bhh   = (const float*)d_in[6];
  const float* wg    = (const float*)d_in[7];
  const float* bg    = (const float*)d_in[8];
  float* out = (float*)d_out;

  char* ws = (char*)d_ws;
  u16* acat   = (u16*)(ws);             // [512 R][48 kb][512] bf16 = 25,165,824 B
  u16* wcat   = (u16*)(ws + 25165824);  // [192 gc][48 kb][512] bf16 =  9,437,184 B
  u16* hdecRM = (u16*)(ws + 34603008);  // [8192][1024] bf16        = 16,777,216 B (end 51,380,224)

  cvt_frag<<<4352, 256, 0, stream>>>(x, wih, whh, acat, wcat);
  decay_frag<<<4096, 256, 0, stream>>>(h, delta, wg, bg, acat, hdecRM);
  gru_gemm<<<dim3(B_N / 128, H_N / 64), 256, 0, stream>>>(acat, wcat, hdecRM, bih, bhh, out);
}